// Round 1
// baseline (581.244 us; speedup 1.0000x reference)
//
#include <hip/hip_runtime.h>
#include <math.h>

// CRF LLH, B=512,S=512,C=96.
// Denominator kernel: 32 blocks x 128thr; each block owns 16 chains.
//  wave0: recurrence via MFMA 16x16x32_f16 (A = W*exp(em) [16 chains x 96],
//         B = exp(trans) held in registers, 18 MFMA/step), single-wave ->
//         no s_barrier on the critical path. State W kept UNNORMALIZED in
//         LDS [k][16] fp16; exact power-of-2 scale 2^-(K+6) applied per
//         step (K = exponent of written max, reduced with an in-group DPP
//         butterfly DEFERRED into the next step's tr-read latency window).
//         C-frag -> A-frag transport: 6x ds_write_b64 + 6x ds_read_b64_tr_b16.
//  wave1: producer; stages exp(em) fp16 tiles + mask flags into a 16-slot
//         LDS ring, ~7 steps ahead; lgkm-only barrier every 4 steps.
// Numerator kernel: 512 blocks (tag-path gather), unchanged logic from the
// previous verified kernel. Both atomicAdd into the scalar output.

#define BATCH 512
#define SEQ   512
#define NC    96
#define CH    16
#define NBLK  (BATCH/CH)
#define NTHR  128
#define LN2   0.69314718055994531f
#define FPAT  0x0001000100010001ull

typedef __fp16 half2v __attribute__((ext_vector_type(2)));
typedef __fp16 half8  __attribute__((ext_vector_type(8)));
typedef float  f32x4  __attribute__((ext_vector_type(4)));
typedef unsigned int uint2v __attribute__((ext_vector_type(2)));
typedef unsigned int uint4v __attribute__((ext_vector_type(4)));

// lgkm-only barrier (keeps global prefetch in flight)
#define BARRIER() asm volatile("s_waitcnt lgkmcnt(0)\n\ts_barrier" ::: "memory")

#define DPP_STEP_F(v, op, ctrl)                                              \
    v = op(v, __int_as_float(__builtin_amdgcn_update_dpp(                    \
            __float_as_int(v), __float_as_int(v), (ctrl), 0xf, 0xf, false)))

__device__ __forceinline__ float wave_max_all(float v) {
    DPP_STEP_F(v, fmaxf, 0x111);
    DPP_STEP_F(v, fmaxf, 0x112);
    DPP_STEP_F(v, fmaxf, 0x114);
    DPP_STEP_F(v, fmaxf, 0x118);
    DPP_STEP_F(v, fmaxf, 0x142);
    DPP_STEP_F(v, fmaxf, 0x143);
    return __int_as_float(__builtin_amdgcn_readlane(__float_as_int(v), 63));
}
__device__ __forceinline__ float fadd_(float a, float b) { return a + b; }
__device__ __forceinline__ float wave_sum_all(float v) {
    DPP_STEP_F(v, fadd_, 0x111);
    DPP_STEP_F(v, fadd_, 0x112);
    DPP_STEP_F(v, fadd_, 0x114);
    DPP_STEP_F(v, fadd_, 0x118);
    DPP_STEP_F(v, fadd_, 0x142);
    DPP_STEP_F(v, fadd_, 0x143);
    return __int_as_float(__builtin_amdgcn_readlane(__float_as_int(v), 63));
}
// butterfly max over each 16-lane group: quad xor1, quad xor2, half_mirror(^7), mirror(^15)
__device__ __forceinline__ float grp16_max(float v) {
    DPP_STEP_F(v, fmaxf, 0xB1);
    DPP_STEP_F(v, fmaxf, 0x4E);
    DPP_STEP_F(v, fmaxf, 0x141);
    DPP_STEP_F(v, fmaxf, 0x140);
    return v;
}
__device__ __forceinline__ unsigned pk_rtn(float a, float b) {
    half2v h; h[0] = (__fp16)a; h[1] = (__fp16)b;
    return __builtin_bit_cast(unsigned, h);
}
__device__ __forceinline__ float dot8(half8 a, uint4v b, float c) {
    uint4v au = __builtin_bit_cast(uint4v, a);
    c = __builtin_amdgcn_fdot2(__builtin_bit_cast(half2v, au.x), __builtin_bit_cast(half2v, b.x), c, false);
    c = __builtin_amdgcn_fdot2(__builtin_bit_cast(half2v, au.y), __builtin_bit_cast(half2v, b.y), c, false);
    c = __builtin_amdgcn_fdot2(__builtin_bit_cast(half2v, au.z), __builtin_bit_cast(half2v, b.z), c, false);
    c = __builtin_amdgcn_fdot2(__builtin_bit_cast(half2v, au.w), __builtin_bit_cast(half2v, b.w), c, false);
    return c;
}

__global__ __launch_bounds__(NTHR, 1)
void crf_denom_kernel(const float* __restrict__ em,      // (B,S,C)
                      const int*   __restrict__ masks,   // (B,S)
                      const float* __restrict__ startT,  // (C)
                      const float* __restrict__ endT,    // (C)
                      const float* __restrict__ trans,   // (C,C)
                      float*       __restrict__ out)
{
    const int tid = threadIdx.x;
    const int l   = tid & 63;
    const int w   = tid >> 6;
    const int c0  = blockIdx.x * CH;
    const int grp = l >> 4;
    const int lid = l & 15;

    __shared__ __align__(16) __fp16 Wl[NC * CH];         // 3 KB, [k][chain]
    __shared__ __align__(16) __fp16 EMR[16][CH * 104];   // exp(em) ring, padded rows
    __shared__ __align__(8)  unsigned short FLG[16][CH]; // mask flags ring
    __shared__ __align__(16) __fp16 ENDX[NC];            // exp(end)
    __shared__ int SKC[CH];

    if (w == 0) {
        // ================= compute wave =================
        float Ms;
        {
            float a = startT[l];
            float b = (l < 32) ? startT[64 + l] : -1e30f;
            Ms = wave_max_all(fmaxf(a, b));
        }
        if (l < 48)
            ((unsigned*)ENDX)[l] = pk_rtn(__expf(endT[2 * l]), __expf(endT[2 * l + 1]));
        // W_0 = exp(start - Ms), same value for all 16 chains of a k-row
        #pragma unroll
        for (int t = 0; t < 12; ++t) {
            const int di = t * 64 + l;
            const int k  = di >> 3;
            const float v0 = __expf(startT[k] - Ms);
            ((unsigned*)Wl)[di] = pk_rtn(v0, v0);
        }
        // B-fragments: E[k][col] = exp(trans[k][col]); lane holds col=16*nt+lid, k=32*t+8*grp+j
        half8 Eb[3][6];
        #pragma unroll
        for (int t = 0; t < 3; ++t)
            #pragma unroll
            for (int nt = 0; nt < 6; ++nt) {
                half8 bv;
                #pragma unroll
                for (int j = 0; j < 8; ++j)
                    bv[j] = (__fp16)__expf(trans[(32 * t + grp * 8 + j) * NC + nt * 16 + lid]);
                Eb[t][nt] = bv;
            }

        const unsigned wtr = (unsigned)(unsigned long long)Wl + (unsigned)(grp * 256);
        char* const wpc    = (char*)Wl + lid * 32 + grp * 8;
        const int   emoff  = lid * 104 + grp * 8;   // halfs

        half8 ap0{}, ap1{}, ap2{};
        float m0 = 1.f, m1 = 1.f, m2 = 1.f, m3 = 1.f;
        float scl0 = 1.f, scl1 = 1.f, scl2 = 1.f, scl3 = 1.f;
        int   ks0 = 0, ks1 = 0, ks2 = 0, ks3 = 0;
        int   sk0 = 0, sk1 = 0, sk2 = 0, sk3 = 0;

        #pragma unroll 1
        for (int s = 1; s <= SEQ - 1; ++s) {
            if ((s & 3) == 1) BARRIER();
            const int slotc = (s - 1) & 15;
            const unsigned long long fqp =
                *(const unsigned long long*)(&FLG[slotc][grp * 4]);
            uint2v t0, t1, t2, t3, t4, t5;
            asm volatile("ds_read_b64_tr_b16 %0, %1"             : "=v"(t0) : "v"(wtr) : "memory");
            asm volatile("ds_read_b64_tr_b16 %0, %1 offset:128"  : "=v"(t1) : "v"(wtr) : "memory");
            asm volatile("ds_read_b64_tr_b16 %0, %1 offset:1024" : "=v"(t2) : "v"(wtr) : "memory");
            asm volatile("ds_read_b64_tr_b16 %0, %1 offset:1152" : "=v"(t3) : "v"(wtr) : "memory");
            asm volatile("ds_read_b64_tr_b16 %0, %1 offset:2048" : "=v"(t4) : "v"(wtr) : "memory");
            asm volatile("ds_read_b64_tr_b16 %0, %1 offset:2176" : "=v"(t5) : "v"(wtr) : "memory");
            const __fp16* emp = &EMR[slotc][0] + emoff;
            const uint4v e0 = *(const uint4v*)(emp);
            const uint4v e1 = *(const uint4v*)(emp + 32);
            const uint4v e2 = *(const uint4v*)(emp + 64);
            const int allp = __all(fqp == FPAT);

            // deferred bookkeeping for step s-1 (fills tr-read latency):
            // K_{s-1} from max of written W_{s-1}; account sumk gated by mask[s-1]
            m0 = grp16_max(m0); m1 = grp16_max(m1);
            m2 = grp16_max(m2); m3 = grp16_max(m3);
            const unsigned eb0 = (__float_as_uint(m0) >> 23) & 255u;
            const unsigned eb1 = (__float_as_uint(m1) >> 23) & 255u;
            const unsigned eb2 = (__float_as_uint(m2) >> 23) & 255u;
            const unsigned eb3 = (__float_as_uint(m3) >> 23) & 255u;
            if (allp) {
                sk0 += ks0; sk1 += ks1; sk2 += ks2; sk3 += ks3;
                ks0 = (int)eb0 - 120; ks1 = (int)eb1 - 120;
                ks2 = (int)eb2 - 120; ks3 = (int)eb3 - 120;
                scl0 = __uint_as_float((247u - eb0) << 23);
                scl1 = __uint_as_float((247u - eb1) << 23);
                scl2 = __uint_as_float((247u - eb2) << 23);
                scl3 = __uint_as_float((247u - eb3) << 23);
            } else {
                if ((unsigned)(fqp      ) & 1u) { sk0 += ks0; ks0 = (int)eb0 - 120; scl0 = __uint_as_float((247u - eb0) << 23); }
                if ((unsigned)(fqp >> 16) & 1u) { sk1 += ks1; ks1 = (int)eb1 - 120; scl1 = __uint_as_float((247u - eb1) << 23); }
                if ((unsigned)(fqp >> 32) & 1u) { sk2 += ks2; ks2 = (int)eb2 - 120; scl2 = __uint_as_float((247u - eb2) << 23); }
                if ((unsigned)(fqp >> 48) & 1u) { sk3 += ks3; ks3 = (int)eb3 - 120; scl3 = __uint_as_float((247u - eb3) << 23); }
            }

            asm volatile("s_waitcnt lgkmcnt(0)" ::: "memory");
            __builtin_amdgcn_sched_barrier(0);
            uint4v u4;
            u4.x = t0.x; u4.y = t0.y; u4.z = t1.x; u4.w = t1.y;
            const half8 aw0 = __builtin_bit_cast(half8, u4);
            u4.x = t2.x; u4.y = t2.y; u4.z = t3.x; u4.w = t3.y;
            const half8 aw1 = __builtin_bit_cast(half8, u4);
            u4.x = t4.x; u4.y = t4.y; u4.z = t5.x; u4.w = t5.y;
            const half8 aw2 = __builtin_bit_cast(half8, u4);
            const half8 an0 = aw0 * __builtin_bit_cast(half8, e0);
            const half8 an1 = aw1 * __builtin_bit_cast(half8, e1);
            const half8 an2 = aw2 * __builtin_bit_cast(half8, e2);
            if (allp) { ap0 = an0; ap1 = an1; ap2 = an2; }
            else {
                const bool fc = (FLG[slotc][lid] != 0);
                ap0 = fc ? an0 : ap0;
                ap1 = fc ? an1 : ap1;
                ap2 = fc ? an2 : ap2;
            }

            f32x4 acc[6];
            #pragma unroll
            for (int nt = 0; nt < 6; ++nt) {
                const f32x4 z = {0.f, 0.f, 0.f, 0.f};
                acc[nt] = __builtin_amdgcn_mfma_f32_16x16x32_f16(ap0, Eb[0][nt], z,       0, 0, 0);
                acc[nt] = __builtin_amdgcn_mfma_f32_16x16x32_f16(ap1, Eb[1][nt], acc[nt], 0, 0, 0);
                acc[nt] = __builtin_amdgcn_mfma_f32_16x16x32_f16(ap2, Eb[2][nt], acc[nt], 0, 0, 0);
            }

            float nm0 = -1e30f, nm1 = -1e30f, nm2 = -1e30f, nm3 = -1e30f;
            #pragma unroll
            for (int nt = 0; nt < 6; ++nt) {
                const float u0 = acc[nt][0] * scl0, u1 = acc[nt][1] * scl1;
                const float u2 = acc[nt][2] * scl2, u3 = acc[nt][3] * scl3;
                nm0 = fmaxf(nm0, u0); nm1 = fmaxf(nm1, u1);
                nm2 = fmaxf(nm2, u2); nm3 = fmaxf(nm3, u3);
                uint2v wv; wv.x = pk_rtn(u0, u1); wv.y = pk_rtn(u2, u3);
                *(uint2v*)(wpc + 512 * nt) = wv;
            }
            m0 = nm0; m1 = nm1; m2 = nm2; m3 = nm3;
        }

        // ---- final: V_511 = W_511 * exp(em_511), denominator
        {
            const int slotc = (SEQ - 1) & 15;
            const unsigned long long fqp =
                *(const unsigned long long*)(&FLG[slotc][grp * 4]);
            const int allp = __all(fqp == FPAT);
            if (allp) { sk0 += ks0; sk1 += ks1; sk2 += ks2; sk3 += ks3; }
            else {
                if ((unsigned)(fqp      ) & 1u) sk0 += ks0;
                if ((unsigned)(fqp >> 16) & 1u) sk1 += ks1;
                if ((unsigned)(fqp >> 32) & 1u) sk2 += ks2;
                if ((unsigned)(fqp >> 48) & 1u) sk3 += ks3;
            }
            uint2v t0, t1, t2, t3, t4, t5;
            asm volatile("ds_read_b64_tr_b16 %0, %1"             : "=v"(t0) : "v"(wtr) : "memory");
            asm volatile("ds_read_b64_tr_b16 %0, %1 offset:128"  : "=v"(t1) : "v"(wtr) : "memory");
            asm volatile("ds_read_b64_tr_b16 %0, %1 offset:1024" : "=v"(t2) : "v"(wtr) : "memory");
            asm volatile("ds_read_b64_tr_b16 %0, %1 offset:1152" : "=v"(t3) : "v"(wtr) : "memory");
            asm volatile("ds_read_b64_tr_b16 %0, %1 offset:2048" : "=v"(t4) : "v"(wtr) : "memory");
            asm volatile("ds_read_b64_tr_b16 %0, %1 offset:2176" : "=v"(t5) : "v"(wtr) : "memory");
            const __fp16* emp = &EMR[slotc][0] + emoff;
            const uint4v e0 = *(const uint4v*)(emp);
            const uint4v e1 = *(const uint4v*)(emp + 32);
            const uint4v e2 = *(const uint4v*)(emp + 64);
            asm volatile("s_waitcnt lgkmcnt(0)" ::: "memory");
            __builtin_amdgcn_sched_barrier(0);
            uint4v u4;
            u4.x = t0.x; u4.y = t0.y; u4.z = t1.x; u4.w = t1.y;
            const half8 aw0 = __builtin_bit_cast(half8, u4);
            u4.x = t2.x; u4.y = t2.y; u4.z = t3.x; u4.w = t3.y;
            const half8 aw1 = __builtin_bit_cast(half8, u4);
            u4.x = t4.x; u4.y = t4.y; u4.z = t5.x; u4.w = t5.y;
            const half8 aw2 = __builtin_bit_cast(half8, u4);
            const half8 an0 = aw0 * __builtin_bit_cast(half8, e0);
            const half8 an1 = aw1 * __builtin_bit_cast(half8, e1);
            const half8 an2 = aw2 * __builtin_bit_cast(half8, e2);
            if (allp) { ap0 = an0; ap1 = an1; ap2 = an2; }
            else {
                const bool fc = (FLG[slotc][lid] != 0);
                ap0 = fc ? an0 : ap0;
                ap1 = fc ? an1 : ap1;
                ap2 = fc ? an2 : ap2;
            }
            const __fp16* ex = ENDX + grp * 8;
            const uint4v x0 = *(const uint4v*)(ex);
            const uint4v x1 = *(const uint4v*)(ex + 32);
            const uint4v x2 = *(const uint4v*)(ex + 64);
            float dv = dot8(ap2, x2, dot8(ap1, x1, dot8(ap0, x0, 0.f)));
            dv += __int_as_float(__builtin_amdgcn_ds_swizzle(__float_as_int(dv), 0x401F)); // xor 16
            dv += __int_as_float(__builtin_amdgcn_ds_bpermute((l ^ 32) << 2, __float_as_int(dv))); // xor 32
            if (lid < 4) {
                int skv = sk0;
                if (lid == 1) skv = sk1;
                else if (lid == 2) skv = sk2;
                else if (lid == 3) skv = sk3;
                SKC[grp * 4 + lid] = skv;
            }
            const int skc = SKC[lid];
            const float den = Ms + (float)skc * LN2 + __logf(dv);
            float contrib = (l < 16) ? den : 0.f;
            contrib = wave_sum_all(contrib);
            if (tid == 0) atomicAdd(out, -contrib * (1.0f / (float)BATCH));
        }
    } else {
        // ================= staging wave =================
        const int q  = l;
        const int ch = q >> 2;
        const int cb = (q & 3) * 24;
        const float* emc  = em + (size_t)(c0 + ch) * SEQ * NC + cb;
        const int*   mrow = masks + (size_t)(c0 + ((q < CH) ? q : 0)) * SEQ;

#define STAGE6(SL, V0, V1, V2, V3, V4, V5, FV) do {                           \
        uint4v* _d = (uint4v*)(&EMR[(SL)][ch * 104 + cb]);                    \
        uint4v _w0 = { pk_rtn(__expf((V0).x), __expf((V0).y)),                \
                       pk_rtn(__expf((V0).z), __expf((V0).w)),                \
                       pk_rtn(__expf((V1).x), __expf((V1).y)),                \
                       pk_rtn(__expf((V1).z), __expf((V1).w)) };              \
        uint4v _w1 = { pk_rtn(__expf((V2).x), __expf((V2).y)),                \
                       pk_rtn(__expf((V2).z), __expf((V2).w)),                \
                       pk_rtn(__expf((V3).x), __expf((V3).y)),                \
                       pk_rtn(__expf((V3).z), __expf((V3).w)) };              \
        uint4v _w2 = { pk_rtn(__expf((V4).x), __expf((V4).y)),                \
                       pk_rtn(__expf((V4).z), __expf((V4).w)),                \
                       pk_rtn(__expf((V5).x), __expf((V5).y)) };              \
        _w2.w = pk_rtn(__expf((V5).z), __expf((V5).w));                       \
        _d[0] = _w0; _d[1] = _w1; _d[2] = _w2;                                \
        if (q < CH) FLG[(SL)][q] = (unsigned short)(FV);                      \
    } while (0)

#define LOAD6(E, V0, V1, V2, V3, V4, V5, FV) do {                             \
        const float* _p = emc + (size_t)(E) * NC;                             \
        V0 = *(const float4*)(_p + 0);  V1 = *(const float4*)(_p + 4);        \
        V2 = *(const float4*)(_p + 8);  V3 = *(const float4*)(_p + 12);       \
        V4 = *(const float4*)(_p + 16); V5 = *(const float4*)(_p + 20);       \
        if (q < CH) FV = (mrow[(E)] != 0);                                    \
    } while (0)

        // prologue: stage e = 0..7 (flag[0] forced to 1)
        for (int e = 0; e < 8; ++e) {
            float4 v0, v1, v2, v3, v4, v5; int fv = 1;
            LOAD6(e, v0, v1, v2, v3, v4, v5, fv);
            STAGE6(e, v0, v1, v2, v3, v4, v5, (e == 0) ? 1 : fv);
        }
        float4 a0, a1, a2, a3, a4, a5, b0, b1, b2, b3, b4, b5;
        int fa = 1, fb = 1;
        LOAD6(8, a0, a1, a2, a3, a4, a5, fa);
        LOAD6(9, b0, b1, b2, b3, b4, b5, fb);

        #pragma unroll 1
        for (int s = 1; s <= SEQ - 1; s += 2) {
            if ((s & 3) == 1) BARRIER();
            {
                const int e = s + 7;
                if (e <= SEQ - 1) STAGE6(e & 15, a0, a1, a2, a3, a4, a5, fa);
                const int e2 = s + 9;
                if (e2 <= SEQ - 1) LOAD6(e2, a0, a1, a2, a3, a4, a5, fa);
            }
            const int s2 = s + 1;
            if (s2 <= SEQ - 1) {
                const int e = s2 + 7;
                if (e <= SEQ - 1) STAGE6(e & 15, b0, b1, b2, b3, b4, b5, fb);
                const int e2 = s2 + 9;
                if (e2 <= SEQ - 1) LOAD6(e2, b0, b1, b2, b3, b4, b5, fb);
            }
        }
#undef STAGE6
#undef LOAD6
    }
}

__global__ __launch_bounds__(NTHR, 1)
void crf_numer_kernel(const float* __restrict__ em,
                      const int*   __restrict__ tags,
                      const int*   __restrict__ masks,
                      const float* __restrict__ startT,
                      const float* __restrict__ endT,
                      const float* __restrict__ trans,
                      float*       __restrict__ out)
{
    const int b    = blockIdx.x;
    const int tid  = threadIdx.x;
    const int lane = tid & 63;
    const int wid  = tid >> 6;
    __shared__ float redn[2], redm[2];
    const float* em_b    = em    + (size_t)b * SEQ * NC;
    const int*   tags_b  = tags  + b * SEQ;
    const int*   masks_b = masks + b * SEQ;
    float nsum = 0.f, msum = 0.f;
    #pragma unroll
    for (int kk = 0; kk < SEQ / NTHR; ++kk) {
        const int s  = tid + NTHR * kk;
        const int tg = tags_b[s];
        const int mk = masks_b[s];
        msum += mk ? 1.f : 0.f;
        if (s == 0) {
            nsum += startT[tg] + em_b[tg];
        } else if (mk) {
            nsum += trans[tags_b[s - 1] * NC + tg] + em_b[s * NC + tg];
        }
    }
    nsum = wave_sum_all(nsum);
    msum = wave_sum_all(msum);
    if (lane == 0) { redn[wid] = nsum; redm[wid] = msum; }
    __syncthreads();
    if (tid == 0) {
        const float numer = redn[0] + redn[1];
        const int   cnt   = (int)(redm[0] + redm[1]);
        const int   last  = tags_b[cnt - 1];
        atomicAdd(out, (numer + endT[last]) * (1.0f / (float)BATCH));
    }
}

extern "C" void kernel_launch(void* const* d_in, const int* in_sizes, int n_in,
                              void* d_out, int out_size, void* d_ws, size_t ws_size,
                              hipStream_t stream) {
    const float* em     = (const float*)d_in[0];
    const int*   tags   = (const int*)  d_in[1];
    const int*   masks  = (const int*)  d_in[2];
    const float* startT = (const float*)d_in[3];
    const float* endT   = (const float*)d_in[4];
    const float* trans  = (const float*)d_in[5];
    float* out = (float*)d_out;

    (void)hipMemsetAsync(out, 0, sizeof(float), stream);
    crf_denom_kernel<<<NBLK, NTHR, 0, stream>>>(em, masks, startT, endT, trans, out);
    crf_numer_kernel<<<BATCH, NTHR, 0, stream>>>(em, tags, masks, startT, endT, trans, out);
}